// Round 9
// baseline (561.575 us; speedup 1.0000x reference)
//
#include <hip/hip_runtime.h>
#include <hip/hip_bf16.h>

namespace {
constexpr int NYg = 512, NXg = 512, NCELL = NYg * NXg;
constexpr int TPB = 256;                    // 4 waves/block
constexpr int NBX = 16, NBY = 16, NBLK = 256; // 16x16 blocks of 32x32 cells: every CU
constexpr int BT = 32;                      // block tile edge
constexpr int SW = 36;                      // S LDS width (2-halo)
constexpr int DW = 34;                      // D/Z LDS width (1-halo)
constexpr int NSTEP = 64;
constexpr int NHALO = 272;                  // 36^2 - 32^2 halo ring cells
constexpr int NGRP = 16;                    // two-level reduce: 16 groups of 16 blocks
constexpr float DXc = 100.0f;
// FD * (RHO*G)^3, matching Python left-to-right f64 fold then f32 cast
constexpr double RGd = 910.0 * 9.81;
constexpr float PHYS_C = (float)(3.1e-17 * RGd * RGd * RGd);
}

// module-owned globals (harness never touches __device__ globals)
__device__ float    g_S[NCELL];                // ring cells only; agent-scope atomics
__device__ unsigned g_mxg[NSTEP][NGRP];        // per-group max(D) partials
__device__ unsigned g_cntg[NSTEP][NGRP];       // per-group arrival counts
__device__ unsigned g_mx[NSTEP];               // global max(D) per step
__device__ unsigned g_cnt[NSTEP];              // completed-group count per step
__device__ unsigned g_flag[NSTEP + 1][NBLK];   // per-step ring-ready flags
__device__ unsigned g_barC = 0, g_barG = 0;    // init gen-barrier (replay-safe)

__device__ __forceinline__ void gen_barrier() {   // used ONCE per call (init)
    __syncthreads();
    if (threadIdx.x == 0) {
        __threadfence();
        const unsigned gen = __hip_atomic_load(&g_barG, __ATOMIC_RELAXED,
                                               __HIP_MEMORY_SCOPE_AGENT);
        const unsigned arrived = __hip_atomic_fetch_add(&g_barC, 1u, __ATOMIC_ACQ_REL,
                                                        __HIP_MEMORY_SCOPE_AGENT);
        if (arrived == NBLK - 1) {
            __hip_atomic_store(&g_barC, 0u, __ATOMIC_RELAXED, __HIP_MEMORY_SCOPE_AGENT);
            __hip_atomic_fetch_add(&g_barG, 1u, __ATOMIC_RELEASE, __HIP_MEMORY_SCOPE_AGENT);
        } else {
            while (__hip_atomic_load(&g_barG, __ATOMIC_ACQUIRE,
                                     __HIP_MEMORY_SCOPE_AGENT) == gen)
                __builtin_amdgcn_s_sleep(2);
        }
        __threadfence();
    }
    __syncthreads();
}

// coherent word access (agent-scope relaxed atomics; cross-XCD proven R7/R8)
__device__ __forceinline__ void coh_store(float* p, float v) {
    __hip_atomic_store(p, v, __ATOMIC_RELAXED, __HIP_MEMORY_SCOPE_AGENT);
}
__device__ __forceinline__ float coh_load(const float* p) {
    return __hip_atomic_load(p, __ATOMIC_RELAXED, __HIP_MEMORY_SCOPE_AGENT);
}

// ---- wire-format probe (R4-validated: wire is f32; probe kept for safety) ----
__device__ __forceinline__ bool wire_f32(const void* zt) {
    const unsigned short* u = (const unsigned short*)zt;
    unsigned short a16 = u[0], c16 = u[2];
    const float a = __bfloat162float(*(const __hip_bfloat16*)&a16);
    const float c = __bfloat162float(*(const __hip_bfloat16*)&c16);
    return !((a > 500.0f) && (a < 5000.0f) && (c > 500.0f) && (c < 5000.0f));
}
__device__ __forceinline__ float ldin(const void* p, int i, bool f32) {
    return f32 ? ((const float*)p)[i] : __bfloat162float(((const __hip_bfloat16*)p)[i]);
}
__device__ __forceinline__ void stout(void* p, int i, float v, bool f32) {
    if (f32) ((float*)p)[i] = v;
    else     ((__hip_bfloat16*)p)[i] = __float2bfloat16(v);
}

__global__ __launch_bounds__(TPB) void GlacierDynamicsCheckpointed_41412074668209_kernel(
    const void* __restrict__ Zt, const void* __restrict__ Hi,
    const void* __restrict__ Mk, const void* __restrict__ Pd,
    const void* __restrict__ Td, const void* __restrict__ Mf,
    void* __restrict__ Out)
{
    __shared__ float Sl[SW * SW];                 // S, 2-halo — LDS-resident all run
    __shared__ float Zl[DW * DW];                 // Z, 1-halo (static)
    __shared__ float Dl[DW * DW];                 // D, 1-halo (per step)
    __shared__ float Ts[512], Ps[512], Js[512];   // sorted T | prefP | suffT
    __shared__ float wred[4];

    const bool f32 = wire_f32(Zt);
    const int tid = threadIdx.x, b = blockIdx.x;
    const int by = b >> 4, bx = b & 15;
    const int grp = by;                           // 16 groups of 16 blocks
    const int ty0 = by * BT, tx0 = bx * BT;
    const int col = tid & 31, r0 = tid >> 5;      // thread owns rows r0+8k, k=0..3
    const float mf = ldin(Mf, 0, f32);

    float H[4], SMB[4];
    bool  Mb[4], Ring[4];

    // ---- init: decode inputs; Sl interior; ring->g_S; Zl; zero sync slots ----
    #pragma unroll
    for (int k = 0; k < 4; ++k) {
        const int r = r0 + 8 * k;
        const int g = (ty0 + r) * NXg + tx0 + col;
        const float z = ldin(Zt, g, f32);
        const float h = ldin(Hi, g, f32);
        H[k]  = h;
        Mb[k] = ldin(Mk, g, f32) > 0.5f;
        Ring[k] = (r < 2) | (r >= BT - 2) | (col < 2) | (col >= BT - 2);
        Sl[(r + 2) * SW + col + 2] = z + h;
        if (Ring[k]) coh_store(&g_S[g], z + h);   // frame(0), coherent
    }
    for (int i = tid; i < DW * DW; i += TPB) {
        const int lr = i / DW, lc = i % DW;
        const int gy = min(max(ty0 - 1 + lr, 0), NYg - 1);
        const int gx = min(max(tx0 - 1 + lc, 0), NXg - 1);
        Zl[i] = ldin(Zt, gy * NXg + gx, f32);
    }
    {   // zero per-step sync slots (distributed over the whole grid)
        const int gb = b * TPB + tid;
        constexpr int NG = NSTEP * NGRP;
        if (gb < NG) ((unsigned*)g_mxg)[gb] = 0u;
        else if (gb < 2 * NG) ((unsigned*)g_cntg)[gb - NG] = 0u;
        else if (gb < 2 * NG + NSTEP) g_mx[gb - 2 * NG] = 0u;
        else if (gb < 2 * NG + 2 * NSTEP) g_cnt[gb - 2 * NG - NSTEP] = 0u;
        else if (gb < 2 * NG + 2 * NSTEP + (NSTEP + 1) * NBLK)
            ((unsigned*)g_flag)[gb - 2 * NG - 2 * NSTEP] = 0u;
    }

    auto load_halo = [&]() {                      // 272 halo cells <- g_S (coherent)
        for (int i = tid; i < NHALO; i += TPB) {
            int lr, lc;
            if (i < 72)       { lr = i / 36;               lc = i % 36; }
            else if (i < 144) { const int j = i - 72;  lr = 34 + j / 36; lc = j % 36; }
            else if (i < 208) { const int j = i - 144; lr = 2 + (j & 31); lc = j >> 5; }
            else              { const int j = i - 208; lr = 2 + (j & 31); lc = 34 + (j >> 5); }
            const int gy = min(max(ty0 - 2 + lr, 0), NYg - 1);
            const int gx = min(max(tx0 - 2 + lc, 0), NXg - 1);
            Sl[lr * SW + lc] = coh_load(&g_S[gy * NXg + gx]);
        }
    };

    int sortedYear = -1;
    // degree-day SMB via sort + prefix/suffix tables (R5/R7/R8-validated numerics)
    auto smb_refresh = [&](int yi) {
        if (yi != sortedYear) {
            sortedYear = yi;
            __syncthreads();
            for (int i = tid; i < 512; i += TPB) {
                if (i < 365) { Ts[i] = ldin(Td, yi * 365 + i, f32);
                               Ps[i] = ldin(Pd, yi * 365 + i, f32); }
                else         { Ts[i] = 3.0e38f; Ps[i] = 0.0f; }
            }
            __syncthreads();
            for (int kk = 2; kk <= 512; kk <<= 1)         // bitonic (T key, P payload)
                for (int j = kk >> 1; j > 0; j >>= 1) {
                    for (int i = tid; i < 512; i += TPB) {
                        const int ixj = i ^ j;
                        if (ixj > i) {
                            const bool up = ((i & kk) == 0);
                            const float a = Ts[i], c = Ts[ixj];
                            if ((a > c) == up) {
                                Ts[i] = c; Ts[ixj] = a;
                                const float p = Ps[i]; Ps[i] = Ps[ixj]; Ps[ixj] = p;
                            }
                        }
                    }
                    __syncthreads();
                }
            for (int i = tid; i < 512; i += TPB) Js[i] = (i < 365) ? Ts[i] : 0.0f;
            __syncthreads();
            for (int off = 1; off < 512; off <<= 1) {     // prefix(P) | suffix(T)
                const int i0 = tid, i1 = tid + 256;
                const float p0 = Ps[i0] + ((i0 >= off) ? Ps[i0 - off] : 0.0f);
                const float p1 = Ps[i1] + ((i1 >= off) ? Ps[i1 - off] : 0.0f);
                const float q0 = Js[i0] + ((i0 + off < 512) ? Js[i0 + off] : 0.0f);
                const float q1 = Js[i1] + ((i1 + off < 512) ? Js[i1 + off] : 0.0f);
                __syncthreads();
                Ps[i0] = p0; Ps[i1] = p1; Js[i0] = q0; Js[i1] = q1;
                __syncthreads();
            }
        }
        #pragma unroll
        for (int k = 0; k < 4; ++k) {
            const int r = r0 + 8 * k;
            const float zs = Sl[(r + 2) * SW + col + 2];  // current surface
            const float u = 0.006f * (zs - 1500.0f);      // GAMMA*(Zs-Z_REF)
            int lo = 0, hi = 365;                          // first idx with T > u
            while (lo < hi) { const int mid = (lo + hi) >> 1;
                              if (Ts[mid] <= u) lo = mid + 1; else hi = mid; }
            const float acc = (lo > 0) ? Ps[lo - 1] : 0.0f;
            const float pdd = (lo < 365)
                ? fmaxf(Js[lo] - u * (float)(365 - lo), 0.0f) : 0.0f;
            SMB[k] = Mb[k] ? (acc - mf * pdd) : -10.0f;    // mask==0 -> -10
        }
    };

    __syncthreads();
    smb_refresh(115);                              // year_idx(1979.0)=115, init surface
    gen_barrier();                                 // slots zeroed + frame(0) visible

    float t = 1979.0f, t_last = 0.0f;
    int prev_yi = 115;
    bool c26 = false, c57 = false, c80 = false;

    for (int step = 0; step < NSTEP; ++step) {
        // ---- 1. neighbor ring wait (pairwise flags) + coherent halo load ----
        if (step > 0) {
            if (tid < 8) {
                const int d = (tid < 4) ? tid : tid + 1;   // skip (0,0)
                const int nby = by + d / 3 - 1, nbx = bx + d % 3 - 1;
                if (nby >= 0 && nby < NBY && nbx >= 0 && nbx < NBX) {
                    const int nb = nby * NBX + nbx;
                    while (__hip_atomic_load(&g_flag[step][nb], __ATOMIC_ACQUIRE,
                                             __HIP_MEMORY_SCOPE_AGENT) == 0u)
                        __builtin_amdgcn_s_sleep(1);
                }
            }
            __syncthreads();
        }
        load_halo();
        __syncthreads();

        // ---- 2. D on 1-halo + block max ----
        float dmax = 0.0f;
        for (int i = tid; i < DW * DW; i += TPB) {
            const int lr = i / DW, lc = i % DW;
            const int gy = ty0 - 1 + lr, gx = tx0 - 1 + lc;   // may be off-grid
            const int si = (lr + 1) * SW + (lc + 1);
            const float sc = Sl[si];
            const int cgx = min(max(gx, 0), NXg - 1), cgy = min(max(gy, 0), NYg - 1);
            // jnp.gradient: central interior, one-sided first-order edges
            const float gxv = (cgx == 0)       ? (Sl[si + 1] - sc) / DXc
                            : (cgx == NXg - 1) ? (sc - Sl[si - 1]) / DXc
                                               : (Sl[si + 1] - Sl[si - 1]) / (2.0f * DXc);
            const float gyv = (cgy == 0)       ? (Sl[si + SW] - sc) / DXc
                            : (cgy == NYg - 1) ? (sc - Sl[si - SW]) / DXc
                                               : (Sl[si + SW] - Sl[si - SW]) / (2.0f * DXc);
            const float h = sc - Zl[i];
            const float h2 = h * h;
            const float D = (PHYS_C * (h2 * h2 * h)) * (gxv * gxv + gyv * gyv);
            Dl[i] = D;
            if (gy >= 0 && gy < NYg && gx >= 0 && gx < NXg) dmax = fmaxf(dmax, D);
        }
        for (int off = 32; off; off >>= 1) dmax = fmaxf(dmax, __shfl_down(dmax, off));
        if ((tid & 63) == 0) wred[tid >> 6] = dmax;
        __syncthreads();

        // ---- 3a. two-level max-reduce: post group partial (NO wait yet) ----
        if (tid == 0) {
            const float m = fmaxf(fmaxf(wred[0], wred[1]), fmaxf(wred[2], wred[3]));
            atomicMax(&g_mxg[step][grp], __float_as_uint(m));  // D>=0: uint==float order
            const unsigned old = __hip_atomic_fetch_add(&g_cntg[step][grp], 1u,
                                     __ATOMIC_ACQ_REL, __HIP_MEMORY_SCOPE_AGENT);
            if (old == NGRP - 1) {                 // last of 16: forward group max
                const unsigned gm = __hip_atomic_load(&g_mxg[step][grp], __ATOMIC_RELAXED,
                                                      __HIP_MEMORY_SCOPE_AGENT);
                atomicMax(&g_mx[step], gm);
                __hip_atomic_fetch_add(&g_cnt[step], 1u,
                                       __ATOMIC_ACQ_REL, __HIP_MEMORY_SCOPE_AGENT);
            }
        }

        // ---- 3b. dt-independent divergence — hides the barrier latency ----
        float divv[4];
        #pragma unroll
        for (int k = 0; k < 4; ++k) {
            const int r = r0 + 8 * k;
            const int gy = ty0 + r, gx = tx0 + col;
            const int si = (r + 2) * SW + col + 2;
            const int di = (r + 1) * DW + col + 1;
            const float sc = Sl[si], dc = Dl[di];
            float qxR = 0.0f, qxL = 0.0f, qyU = 0.0f, qyD = 0.0f;  // zero-flux bnd
            if (gx < NXg - 1) qxR = 0.5f * (Dl[di + 1] + dc)  * ((Sl[si + 1] - sc)  / DXc);
            if (gx > 0)       qxL = 0.5f * (dc + Dl[di - 1])  * ((sc - Sl[si - 1])  / DXc);
            if (gy < NYg - 1) qyU = 0.5f * (Dl[di + DW] + dc) * ((Sl[si + SW] - sc) / DXc);
            if (gy > 0)       qyD = 0.5f * (dc + Dl[di - DW]) * ((sc - Sl[si - SW]) / DXc);
            divv[k] = (qxR - qxL) / DXc + (qyU - qyD) / DXc;
        }
        __syncthreads();                           // divv reads done; Sl may be rewritten

        // ---- 3c. complete the barrier (16 groups), fetch global max ----
        if (tid == 0) {
            while (__hip_atomic_load(&g_cnt[step], __ATOMIC_ACQUIRE,
                                     __HIP_MEMORY_SCOPE_AGENT) < NGRP)
                __builtin_amdgcn_s_sleep(2);
            wred[0] = __uint_as_float(__hip_atomic_load(&g_mx[step], __ATOMIC_RELAXED,
                                                        __HIP_MEMORY_SCOPE_AGENT));
        }
        __syncthreads();
        const float maxD = wred[0];

        // ---- 4. dt, H update, Sl rewrite, ring publish (from registers) ----
        const float dt = fminf(0.1f, 2000.0f / (maxD + 1e-6f));   // CFL*dx^2 = 2000
        const float tn = t + dt;
        const bool hit26 = !c26 && (tn >= 1926.0f);
        const bool hit57 = !c57 && (tn >= 1957.0f);
        const bool hit80 = !c80 && (tn >= 1980.0f);
        #pragma unroll
        for (int k = 0; k < 4; ++k) {
            const int r = r0 + 8 * k;
            const int si = (r + 2) * SW + col + 2;
            const int di = (r + 1) * DW + col + 1;
            const float hn = fmaxf(H[k] + dt * (SMB[k] + divv[k]), 0.0f);
            H[k] = hn;
            const float s_new = Zl[di] + hn;
            Sl[si] = s_new;
            if (Ring[k]) coh_store(&g_S[(ty0 + r) * NXg + tx0 + col], s_new);
        }
        __syncthreads();                           // drains vmcnt: ring stores retired

        // ---- 5. flag ASAP, then snapshots + SMB refresh off the critical path ----
        if (tid == 0)
            __hip_atomic_store(&g_flag[step + 1][b], 1u, __ATOMIC_RELEASE,
                               __HIP_MEMORY_SCOPE_AGENT);
        if (hit26 | hit57 | hit80) {
            #pragma unroll
            for (int k = 0; k < 4; ++k) {
                const int g = (ty0 + r0 + 8 * k) * NXg + tx0 + col;
                if (hit26) stout(Out, g, H[k], f32);
                if (hit57) stout(Out, NCELL + g, H[k], f32);
                if (hit80) stout(Out, 2 * NCELL + g, H[k], f32);
            }
        }
        c26 |= hit26; c57 |= hit57; c80 |= hit80;

        int yi = (int)floorf(tn - 1864.0f);
        yi = min(max(yi, 0), 127);
        const bool need = (yi != prev_yi) || (tn - t_last >= 10.0f);
        if (need) {
            t_last = tn; prev_yi = yi;
            if (tn < 1981.0f) smb_refresh(yi);     // past TTOT: unobservable, skip
        }
        t = tn;
        if (t >= 1981.0f) break;                   // uniform across grid (same dt chain)
    }

    // ---- finals: H always; zeros for untriggered snapshots ----
    #pragma unroll
    for (int k = 0; k < 4; ++k) {
        const int g = (ty0 + r0 + 8 * k) * NXg + tx0 + col;
        stout(Out, 3 * NCELL + g, H[k], f32);
        if (!c26) stout(Out, g, 0.0f, f32);
        if (!c57) stout(Out, NCELL + g, 0.0f, f32);
        if (!c80) stout(Out, 2 * NCELL + g, 0.0f, f32);
    }
}

extern "C" void kernel_launch(void* const* d_in, const int* in_sizes, int n_in,
                              void* d_out, int out_size, void* d_ws, size_t ws_size,
                              hipStream_t stream) {
    (void)in_sizes; (void)n_in; (void)out_size; (void)d_ws; (void)ws_size;
    const void* Zt = d_in[0];   // Z_topo
    const void* Hi = d_in[1];   // H_init
    const void* Mk = d_in[2];   // ice_mask
    // d_in[3] precip_tensor, d_in[4] T_m_lowest, d_in[5] T_s: unused by reference
    const void* Pd = d_in[6];   // P_daily
    const void* Td = d_in[7];   // T_daily
    const void* Mf = d_in[8];   // melt_factor
    hipLaunchKernelGGL(GlacierDynamicsCheckpointed_41412074668209_kernel,
                       dim3(NBLK), dim3(TPB), 0, stream,
                       Zt, Hi, Mk, Pd, Td, Mf, d_out);
}

// Round 10
// 342.124 us; speedup vs baseline: 1.6414x; 1.6414x over previous
//
#include <hip/hip_runtime.h>
#include <hip/hip_bf16.h>

namespace {
constexpr int NYg = 512, NXg = 512, NCELL = NYg * NXg;
constexpr int TPB = 512;                   // 8 waves/block
constexpr int NBX = 8, NBY = 8, NBLK = 64; // 8x8 blocks of 64x64 cells (R8-proven)
constexpr int BT = 64;                     // block tile edge
constexpr int SW = 68;                     // S LDS width (2-halo)
constexpr int DW = 66;                     // D/Z LDS width (1-halo)
constexpr int NSTEP = 64;
constexpr int NHALO = 528;                 // 68^2 - 64^2 halo ring cells
constexpr float I1HX = 0.01f;              // 1/DX   (div->mul: ~1ulp deviation, safe)
constexpr float I2HX = 0.005f;             // 1/(2DX)
// FD * (RHO*G)^3, matching Python left-to-right f64 fold then f32 cast
constexpr double RGd = 910.0 * 9.81;
constexpr float PHYS_C = (float)(3.1e-17 * RGd * RGd * RGd);
}

// module-owned globals (harness never touches __device__ globals)
__device__ float    g_S[NCELL];              // ring cells only; agent-scope atomics
__device__ unsigned g_cnt[NSTEP];            // per-step barrier arrival counts
__device__ unsigned g_mx[NSTEP];             // per-step max(D) as ordered uint
__device__ unsigned g_flag[NSTEP + 1][NBLK]; // per-step ring-ready flags
__device__ unsigned g_barC = 0, g_barG = 0;  // init gen-barrier (replay-safe)

__device__ __forceinline__ void gen_barrier() {   // used ONCE per call (init)
    __syncthreads();
    if (threadIdx.x == 0) {
        __threadfence();
        const unsigned gen = __hip_atomic_load(&g_barG, __ATOMIC_RELAXED,
                                               __HIP_MEMORY_SCOPE_AGENT);
        const unsigned arrived = __hip_atomic_fetch_add(&g_barC, 1u, __ATOMIC_ACQ_REL,
                                                        __HIP_MEMORY_SCOPE_AGENT);
        if (arrived == NBLK - 1) {
            __hip_atomic_store(&g_barC, 0u, __ATOMIC_RELAXED, __HIP_MEMORY_SCOPE_AGENT);
            __hip_atomic_fetch_add(&g_barG, 1u, __ATOMIC_RELEASE, __HIP_MEMORY_SCOPE_AGENT);
        } else {
            while (__hip_atomic_load(&g_barG, __ATOMIC_ACQUIRE,
                                     __HIP_MEMORY_SCOPE_AGENT) == gen)
                __builtin_amdgcn_s_sleep(2);
        }
        __threadfence();
    }
    __syncthreads();
}

// coherent word access (agent-scope relaxed atomics; cross-XCD proven R7/R8)
__device__ __forceinline__ void coh_store(float* p, float v) {
    __hip_atomic_store(p, v, __ATOMIC_RELAXED, __HIP_MEMORY_SCOPE_AGENT);
}
__device__ __forceinline__ float coh_load(const float* p) {
    return __hip_atomic_load(p, __ATOMIC_RELAXED, __HIP_MEMORY_SCOPE_AGENT);
}

// ---- wire-format probe (R4-validated: wire is f32; probe kept for safety) ----
__device__ __forceinline__ bool wire_f32(const void* zt) {
    const unsigned short* u = (const unsigned short*)zt;
    unsigned short a16 = u[0], c16 = u[2];
    const float a = __bfloat162float(*(const __hip_bfloat16*)&a16);
    const float c = __bfloat162float(*(const __hip_bfloat16*)&c16);
    return !((a > 500.0f) && (a < 5000.0f) && (c > 500.0f) && (c < 5000.0f));
}
__device__ __forceinline__ float ldin(const void* p, int i, bool f32) {
    return f32 ? ((const float*)p)[i] : __bfloat162float(((const __hip_bfloat16*)p)[i]);
}
__device__ __forceinline__ void stout(void* p, int i, float v, bool f32) {
    if (f32) ((float*)p)[i] = v;
    else     ((__hip_bfloat16*)p)[i] = __float2bfloat16(v);
}

__global__ __launch_bounds__(TPB) void GlacierDynamicsCheckpointed_41412074668209_kernel(
    const void* __restrict__ Zt, const void* __restrict__ Hi,
    const void* __restrict__ Mk, const void* __restrict__ Pd,
    const void* __restrict__ Td, const void* __restrict__ Mf,
    void* __restrict__ Out)
{
    __shared__ float Sl[SW * SW];                 // S, 2-halo — LDS-resident all run
    __shared__ float Zl[DW * DW];                 // Z, 1-halo (static)
    __shared__ float Dl[DW * DW];                 // D, 1-halo (per step)
    __shared__ float Ts[512], Ps[512], Js[512];   // sorted T | prefP | suffT
    __shared__ float wred[8];

    const bool f32 = wire_f32(Zt);
    const int tid = threadIdx.x, b = blockIdx.x;
    const int by = b >> 3, bx = b & 7;
    const int ty0 = by * BT, tx0 = bx * BT;
    const int col = tid & 63, r0 = tid >> 6;      // thread owns rows r0+8k, k=0..7
    const float mf = ldin(Mf, 0, f32);

    float H[8], SMB[8];
    bool  Mb[8], Ring[8];

    // ---- init: decode inputs; Sl interior; ring->g_S; Zl; zero sync slots ----
    #pragma unroll
    for (int k = 0; k < 8; ++k) {
        const int r = r0 + 8 * k;
        const int g = (ty0 + r) * NXg + tx0 + col;
        const float z = ldin(Zt, g, f32);
        const float h = ldin(Hi, g, f32);
        H[k]  = h;
        Mb[k] = ldin(Mk, g, f32) > 0.5f;
        Ring[k] = (r < 2) | (r >= BT - 2) | (col < 2) | (col >= BT - 2);
        Sl[(r + 2) * SW + col + 2] = z + h;
        if (Ring[k]) coh_store(&g_S[g], z + h);   // frame(0), coherent
    }
    for (int i = tid; i < DW * DW; i += TPB) {
        const int lr = i / DW, lc = i % DW;
        const int gy = min(max(ty0 - 1 + lr, 0), NYg - 1);
        const int gx = min(max(tx0 - 1 + lc, 0), NXg - 1);
        Zl[i] = ldin(Zt, gy * NXg + gx, f32);
    }
    {   // zero per-step sync slots (4288 words, distributed over blocks 0..8)
        const int gb = b * TPB + tid;
        if (gb < NSTEP) g_cnt[gb] = 0u;
        else if (gb < 2 * NSTEP) g_mx[gb - NSTEP] = 0u;
        else if (gb < 2 * NSTEP + (NSTEP + 1) * NBLK)
            ((unsigned*)g_flag)[gb - 2 * NSTEP] = 0u;
    }

    int sortedYear = -1;
    // degree-day SMB via sort + prefix/suffix tables (R5/R7/R8-validated numerics)
    auto smb_refresh = [&](int yi) {
        if (yi != sortedYear) {
            sortedYear = yi;
            __syncthreads();
            if (tid < 365) { Ts[tid] = ldin(Td, yi * 365 + tid, f32);
                             Ps[tid] = ldin(Pd, yi * 365 + tid, f32); }
            else           { Ts[tid] = 3.0e38f; Ps[tid] = 0.0f; }
            __syncthreads();
            for (int kk = 2; kk <= 512; kk <<= 1)         // bitonic (T key, P payload)
                for (int j = kk >> 1; j > 0; j >>= 1) {
                    const int i = tid, ixj = i ^ j;
                    if (ixj > i) {
                        const bool up = ((i & kk) == 0);
                        const float a = Ts[i], c = Ts[ixj];
                        if ((a > c) == up) {
                            Ts[i] = c; Ts[ixj] = a;
                            const float p = Ps[i]; Ps[i] = Ps[ixj]; Ps[ixj] = p;
                        }
                    }
                    __syncthreads();
                }
            Js[tid] = (tid < 365) ? Ts[tid] : 0.0f;
            __syncthreads();
            for (int off = 1; off < 512; off <<= 1) {     // prefix(P) | suffix(T)
                const float p = Ps[tid] + ((tid >= off) ? Ps[tid - off] : 0.0f);
                const float q = Js[tid] + ((tid + off < 512) ? Js[tid + off] : 0.0f);
                __syncthreads();
                Ps[tid] = p; Js[tid] = q;
                __syncthreads();
            }
        }
        #pragma unroll
        for (int k = 0; k < 8; ++k) {
            const int r = r0 + 8 * k;
            const float zs = Sl[(r + 2) * SW + col + 2];  // current surface
            const float u = 0.006f * (zs - 1500.0f);      // GAMMA*(Zs-Z_REF)
            int lo = 0, hi = 365;                          // first idx with T > u
            while (lo < hi) { const int mid = (lo + hi) >> 1;
                              if (Ts[mid] <= u) lo = mid + 1; else hi = mid; }
            const float acc = (lo > 0) ? Ps[lo - 1] : 0.0f;
            const float pdd = (lo < 365)
                ? fmaxf(Js[lo] - u * (float)(365 - lo), 0.0f) : 0.0f;
            SMB[k] = Mb[k] ? (acc - mf * pdd) : -10.0f;    // mask==0 -> -10
        }
    };

    __syncthreads();
    smb_refresh(115);                              // year_idx(1979.0)=115, init surface
    gen_barrier();                                 // slots zeroed + frame(0) visible

    float t = 1979.0f, t_last = 0.0f;
    int prev_yi = 115;
    bool c26 = false, c57 = false, c80 = false;

    // halo slot mapper: i in [0,528) -> (lr,lc) of the 2-deep 68x68 ring
    auto halo_map = [&](int i, int& lr, int& lc) {
        if (i < 136)      { lr = i / 68;               lc = i % 68; }
        else if (i < 272) { const int j = i - 136; lr = 66 + j / 68; lc = j % 68; }
        else if (i < 400) { const int j = i - 272; lr = 2 + (j & 63); lc = j >> 6; }
        else              { const int j = i - 400; lr = 2 + (j & 63); lc = 66 + (j >> 6); }
    };

    for (int step = 0; step < NSTEP; ++step) {
        __syncthreads();          // prior-step Sl writes done before halo overwrite

        // ---- 1. per-thread gated halo loads (staged in regs, overlap with 2) ----
        float hv0 = 0.0f, hv1 = 0.0f;
        int   la0 = -1,   la1 = -1;
        {
            int i = tid;
            if (i < NHALO) {
                int lr, lc; halo_map(i, lr, lc);
                const int cgy = min(max(ty0 - 2 + lr, 0), NYg - 1);
                const int cgx = min(max(tx0 - 2 + lc, 0), NXg - 1);
                la0 = lr * SW + lc;
                const int sb = ((cgy >> 6) << 3) | (cgx >> 6);   // source block
                if (step > 0)
                    while (__hip_atomic_load(&g_flag[step][sb], __ATOMIC_ACQUIRE,
                                             __HIP_MEMORY_SCOPE_AGENT) == 0u)
                        __builtin_amdgcn_s_sleep(1);
                hv0 = coh_load(&g_S[cgy * NXg + cgx]);
            }
            i = tid + TPB;
            if (i < NHALO) {
                int lr, lc; halo_map(i, lr, lc);
                const int cgy = min(max(ty0 - 2 + lr, 0), NYg - 1);
                const int cgx = min(max(tx0 - 2 + lc, 0), NXg - 1);
                la1 = lr * SW + lc;
                const int sb = ((cgy >> 6) << 3) | (cgx >> 6);
                if (step > 0)
                    while (__hip_atomic_load(&g_flag[step][sb], __ATOMIC_ACQUIRE,
                                             __HIP_MEMORY_SCOPE_AGENT) == 0u)
                        __builtin_amdgcn_s_sleep(1);
                hv1 = coh_load(&g_S[cgy * NXg + cgx]);
            }
        }

        // ---- 2. interior D (62^2, no halo dep; never grid-edge) ----
        float dmax = 0.0f;
        if (col < 62) {
            for (int rp = r0; rp < 62; rp += 8) {
                const int lr = rp + 2, lc = col + 2;      // D coords [2,64)
                const int si = (lr + 1) * SW + lc + 1;
                const float gxv = (Sl[si + 1]  - Sl[si - 1])  * I2HX;
                const float gyv = (Sl[si + SW] - Sl[si - SW]) * I2HX;
                const float h = Sl[si] - Zl[lr * DW + lc];
                const float h2 = h * h;
                const float D = (PHYS_C * (h2 * h2 * h)) * (gxv * gxv + gyv * gyv);
                Dl[lr * DW + lc] = D;
                dmax = fmaxf(dmax, D);
            }
        }
        if (la0 >= 0) Sl[la0] = hv0;                      // commit halo to LDS
        if (la1 >= 0) Sl[la1] = hv1;
        __syncthreads();

        // ---- 3. border D (512 frame cells of the 66^2 region) ----
        {
            const int i = tid;
            int lr, lc;
            if (i < 132)      { lr = i / 66;               lc = i % 66; }
            else if (i < 264) { const int j = i - 132; lr = 64 + j / 66; lc = j % 66; }
            else if (i < 388) { const int j = i - 264; lc = j & 1;       lr = 2 + (j >> 1); }
            else              { const int j = i - 388; lc = 64 + (j & 1); lr = 2 + (j >> 1); }
            const int gy = ty0 - 1 + lr, gx = tx0 - 1 + lc;   // may be off-grid
            const int si = (lr + 1) * SW + lc + 1;
            const float sc = Sl[si];
            const int cgx = min(max(gx, 0), NXg - 1), cgy = min(max(gy, 0), NYg - 1);
            const float gxv = (cgx == 0)       ? (Sl[si + 1] - sc) * I1HX
                            : (cgx == NXg - 1) ? (sc - Sl[si - 1]) * I1HX
                                               : (Sl[si + 1] - Sl[si - 1]) * I2HX;
            const float gyv = (cgy == 0)       ? (Sl[si + SW] - sc) * I1HX
                            : (cgy == NYg - 1) ? (sc - Sl[si - SW]) * I1HX
                                               : (Sl[si + SW] - Sl[si - SW]) * I2HX;
            const float h = sc - Zl[lr * DW + lc];
            const float h2 = h * h;
            const float D = (PHYS_C * (h2 * h2 * h)) * (gxv * gxv + gyv * gyv);
            Dl[lr * DW + lc] = D;
            if (gy >= 0 && gy < NYg && gx >= 0 && gx < NXg) dmax = fmaxf(dmax, D);
        }
        for (int off = 32; off; off >>= 1) dmax = fmaxf(dmax, __shfl_down(dmax, off));
        if ((tid & 63) == 0) wred[tid >> 6] = dmax;
        __syncthreads();                          // Dl + wred complete

        // ---- 4a. post arrival at the max-barrier (NO wait yet) ----
        if (tid == 0) {
            float m = wred[0];
            #pragma unroll
            for (int i = 1; i < 8; ++i) m = fmaxf(m, wred[i]);
            atomicMax(&g_mx[step], __float_as_uint(m));      // D>=0: uint==float order
            __hip_atomic_fetch_add(&g_cnt[step], 1u,
                                   __ATOMIC_ACQ_REL, __HIP_MEMORY_SCOPE_AGENT);
        }

        // ---- 4b. dt-independent divergence — hides the barrier latency ----
        float divv[8];
        #pragma unroll
        for (int k = 0; k < 8; ++k) {
            const int r = r0 + 8 * k;
            const int gy = ty0 + r, gx = tx0 + col;
            const int si = (r + 2) * SW + col + 2;
            const int di = (r + 1) * DW + col + 1;
            const float sc = Sl[si], dc = Dl[di];
            float qxR = 0.0f, qxL = 0.0f, qyU = 0.0f, qyD = 0.0f;  // zero-flux bnd
            if (gx < NXg - 1) qxR = 0.5f * (Dl[di + 1] + dc)  * ((Sl[si + 1] - sc)  * I1HX);
            if (gx > 0)       qxL = 0.5f * (dc + Dl[di - 1])  * ((sc - Sl[si - 1])  * I1HX);
            if (gy < NYg - 1) qyU = 0.5f * (Dl[di + DW] + dc) * ((Sl[si + SW] - sc) * I1HX);
            if (gy > 0)       qyD = 0.5f * (dc + Dl[di - DW]) * ((sc - Sl[si - SW]) * I1HX);
            divv[k] = (qxR - qxL) * I1HX + (qyU - qyD) * I1HX;
        }
        __syncthreads();                           // divv reads done; Sl may be rewritten

        // ---- 4c. complete the barrier, fetch global max ----
        if (tid == 0) {
            while (__hip_atomic_load(&g_cnt[step], __ATOMIC_ACQUIRE,
                                     __HIP_MEMORY_SCOPE_AGENT) < NBLK)
                __builtin_amdgcn_s_sleep(1);
            wred[0] = __uint_as_float(__hip_atomic_load(&g_mx[step], __ATOMIC_RELAXED,
                                                        __HIP_MEMORY_SCOPE_AGENT));
        }
        __syncthreads();
        const float maxD = wred[0];

        // ---- 5. dt; RING cells first -> publish -> flag early ----
        const float dt = fminf(0.1f, 2000.0f / (maxD + 1e-6f));   // CFL*dx^2 = 2000
        const float tn = t + dt;
        const bool hit26 = !c26 && (tn >= 1926.0f);
        const bool hit57 = !c57 && (tn >= 1957.0f);
        const bool hit80 = !c80 && (tn >= 1980.0f);
        #pragma unroll
        for (int k = 0; k < 8; ++k) {
            if (Ring[k]) {
                const int r = r0 + 8 * k;
                const int si = (r + 2) * SW + col + 2;
                const int di = (r + 1) * DW + col + 1;
                const float hn = fmaxf(H[k] + dt * (SMB[k] + divv[k]), 0.0f);
                H[k] = hn;
                const float s_new = Zl[di] + hn;
                Sl[si] = s_new;
                coh_store(&g_S[(ty0 + r) * NXg + tx0 + col], s_new);
            }
        }
        __syncthreads();                           // drains vmcnt: ring stores retired
        if (tid == 0)
            __hip_atomic_store(&g_flag[step + 1][b], 1u, __ATOMIC_RELEASE,
                               __HIP_MEMORY_SCOPE_AGENT);

        // ---- 6. interior cells + snapshots off the critical path ----
        #pragma unroll
        for (int k = 0; k < 8; ++k) {
            if (!Ring[k]) {
                const int r = r0 + 8 * k;
                const int si = (r + 2) * SW + col + 2;
                const int di = (r + 1) * DW + col + 1;
                const float hn = fmaxf(H[k] + dt * (SMB[k] + divv[k]), 0.0f);
                H[k] = hn;
                Sl[si] = Zl[di] + hn;
            }
        }
        if (hit26 | hit57 | hit80) {
            #pragma unroll
            for (int k = 0; k < 8; ++k) {
                const int g = (ty0 + r0 + 8 * k) * NXg + tx0 + col;
                if (hit26) stout(Out, g, H[k], f32);
                if (hit57) stout(Out, NCELL + g, H[k], f32);
                if (hit80) stout(Out, 2 * NCELL + g, H[k], f32);
            }
        }
        c26 |= hit26; c57 |= hit57; c80 |= hit80;

        int yi = (int)floorf(tn - 1864.0f);
        yi = min(max(yi, 0), 127);
        const bool need = (yi != prev_yi) || (tn - t_last >= 10.0f);
        if (need) {
            t_last = tn; prev_yi = yi;
            if (tn < 1981.0f) smb_refresh(yi);     // same year -> no re-sort, just search
        }
        t = tn;
        if (t >= 1981.0f) break;                   // uniform across grid (same dt chain)
    }

    // ---- finals: H always; zeros for untriggered snapshots ----
    #pragma unroll
    for (int k = 0; k < 8; ++k) {
        const int g = (ty0 + r0 + 8 * k) * NXg + tx0 + col;
        stout(Out, 3 * NCELL + g, H[k], f32);
        if (!c26) stout(Out, g, 0.0f, f32);
        if (!c57) stout(Out, NCELL + g, 0.0f, f32);
        if (!c80) stout(Out, 2 * NCELL + g, 0.0f, f32);
    }
}

extern "C" void kernel_launch(void* const* d_in, const int* in_sizes, int n_in,
                              void* d_out, int out_size, void* d_ws, size_t ws_size,
                              hipStream_t stream) {
    (void)in_sizes; (void)n_in; (void)out_size; (void)d_ws; (void)ws_size;
    const void* Zt = d_in[0];   // Z_topo
    const void* Hi = d_in[1];   // H_init
    const void* Mk = d_in[2];   // ice_mask
    // d_in[3] precip_tensor, d_in[4] T_m_lowest, d_in[5] T_s: unused by reference
    const void* Pd = d_in[6];   // P_daily
    const void* Td = d_in[7];   // T_daily
    const void* Mf = d_in[8];   // melt_factor
    hipLaunchKernelGGL(GlacierDynamicsCheckpointed_41412074668209_kernel,
                       dim3(NBLK), dim3(TPB), 0, stream,
                       Zt, Hi, Mk, Pd, Td, Mf, d_out);
}

// Round 13
// 284.845 us; speedup vs baseline: 1.9715x; 1.2011x over previous
//
#include <hip/hip_runtime.h>
#include <hip/hip_bf16.h>

namespace {
constexpr int NYg = 512, NXg = 512, NCELL = NYg * NXg;
constexpr int TPB = 512;                   // 8 waves/block
constexpr int NBX = 8, NBY = 8, NBLK = 64; // 8x8 blocks of 64x64 cells (R8-proven)
constexpr int BT = 64;                     // block tile edge
constexpr int SW = 68;                     // S LDS width (2-halo)
constexpr int DW = 66;                     // D/Z LDS width (1-halo)
constexpr int NSTEP = 64;
constexpr int NHALO = 528;                 // 68^2 - 64^2 halo ring cells
constexpr float I1HX = 0.01f;              // 1/DX   (div->mul, R10-validated)
constexpr float I2HX = 0.005f;             // 1/(2DX)
// FD * (RHO*G)^3, matching Python left-to-right f64 fold then f32 cast
constexpr double RGd = 910.0 * 9.81;
constexpr float PHYS_C = (float)(3.1e-17 * RGd * RGd * RGd);
}

// module-owned globals (harness never touches __device__ globals)
__device__ float    g_S[NCELL];              // ring cells only; agent-scope atomics
__device__ unsigned g_bmax[NSTEP][NBLK];     // per-step per-block max(D), ~bits (0=not ready)
__device__ unsigned g_flag[NSTEP + 1][NBLK]; // per-step ring-ready flags
__device__ unsigned g_barC = 0, g_barG = 0;  // init gen-barrier (replay-safe)

__device__ __forceinline__ void gen_barrier() {   // used ONCE per call (init)
    __syncthreads();
    if (threadIdx.x == 0) {
        __threadfence();
        const unsigned gen = __hip_atomic_load(&g_barG, __ATOMIC_RELAXED,
                                               __HIP_MEMORY_SCOPE_AGENT);
        const unsigned arrived = __hip_atomic_fetch_add(&g_barC, 1u, __ATOMIC_ACQ_REL,
                                                        __HIP_MEMORY_SCOPE_AGENT);
        if (arrived == NBLK - 1) {
            __hip_atomic_store(&g_barC, 0u, __ATOMIC_RELAXED, __HIP_MEMORY_SCOPE_AGENT);
            __hip_atomic_fetch_add(&g_barG, 1u, __ATOMIC_RELEASE, __HIP_MEMORY_SCOPE_AGENT);
        } else {
            while (__hip_atomic_load(&g_barG, __ATOMIC_ACQUIRE,
                                     __HIP_MEMORY_SCOPE_AGENT) == gen)
                __builtin_amdgcn_s_sleep(2);
        }
        __threadfence();
    }
    __syncthreads();
}

// coherent word access (agent-scope relaxed atomics; cross-XCD proven R7-R10)
__device__ __forceinline__ void coh_store(float* p, float v) {
    __hip_atomic_store(p, v, __ATOMIC_RELAXED, __HIP_MEMORY_SCOPE_AGENT);
}
__device__ __forceinline__ float coh_load(const float* p) {
    return __hip_atomic_load(p, __ATOMIC_RELAXED, __HIP_MEMORY_SCOPE_AGENT);
}

// ---- wire-format probe (R4-validated: wire is f32; probe kept for safety) ----
__device__ __forceinline__ bool wire_f32(const void* zt) {
    const unsigned short* u = (const unsigned short*)zt;
    unsigned short a16 = u[0], c16 = u[2];
    const float a = __bfloat162float(*(const __hip_bfloat16*)&a16);
    const float c = __bfloat162float(*(const __hip_bfloat16*)&c16);
    return !((a > 500.0f) && (a < 5000.0f) && (c > 500.0f) && (c < 5000.0f));
}
__device__ __forceinline__ float ldin(const void* p, int i, bool f32) {
    return f32 ? ((const float*)p)[i] : __bfloat162float(((const __hip_bfloat16*)p)[i]);
}
__device__ __forceinline__ void stout(void* p, int i, float v, bool f32) {
    if (f32) ((float*)p)[i] = v;
    else     ((__hip_bfloat16*)p)[i] = __float2bfloat16(v);
}

__global__ __launch_bounds__(TPB) void GlacierDynamicsCheckpointed_41412074668209_kernel(
    const void* __restrict__ Zt, const void* __restrict__ Hi,
    const void* __restrict__ Mk, const void* __restrict__ Pd,
    const void* __restrict__ Td, const void* __restrict__ Mf,
    void* __restrict__ Out)
{
    __shared__ float Sl[SW * SW];                 // S, 2-halo — LDS-resident all run
    __shared__ float Zl[DW * DW];                 // Z, 1-halo (static)
    __shared__ float Dl[DW * DW];                 // D, 1-halo (per step)
    __shared__ float Ts[512], Ps[512], Js[512];   // sorted T | prefP | suffT
    __shared__ float wred[8];

    const bool f32 = wire_f32(Zt);
    const int tid = threadIdx.x, b = blockIdx.x;
    const int by = b >> 3, bx = b & 7;
    const int ty0 = by * BT, tx0 = bx * BT;
    const int col = tid & 63, r0 = tid >> 6;      // thread owns rows r0+8k, k=0..7
    const float mf = ldin(Mf, 0, f32);

    float H[8], SMB[8];
    bool  Mb[8], Ring[8];

    // ---- init: decode inputs; Sl interior; ring->g_S; Zl; zero sync slots ----
    #pragma unroll
    for (int k = 0; k < 8; ++k) {
        const int r = r0 + 8 * k;
        const int g = (ty0 + r) * NXg + tx0 + col;
        const float z = ldin(Zt, g, f32);
        const float h = ldin(Hi, g, f32);
        H[k]  = h;
        Mb[k] = ldin(Mk, g, f32) > 0.5f;
        Ring[k] = (r < 2) | (r >= BT - 2) | (col < 2) | (col >= BT - 2);
        Sl[(r + 2) * SW + col + 2] = z + h;
        if (Ring[k]) coh_store(&g_S[g], z + h);   // frame(0), coherent
    }
    for (int i = tid; i < DW * DW; i += TPB) {
        const int lr = i / DW, lc = i % DW;
        const int gy = min(max(ty0 - 1 + lr, 0), NYg - 1);
        const int gx = min(max(tx0 - 1 + lc, 0), NXg - 1);
        Zl[i] = ldin(Zt, gy * NXg + gx, f32);
    }
    {   // zero per-step sync slots (8256 words, distributed over blocks 0..16)
        const int gb = b * TPB + tid;
        if (gb < NSTEP * NBLK) ((unsigned*)g_bmax)[gb] = 0u;
        else if (gb < NSTEP * NBLK + (NSTEP + 1) * NBLK)
            ((unsigned*)g_flag)[gb - NSTEP * NBLK] = 0u;
    }

    auto load_halo = [&]() {                      // 528 halo cells <- g_S (coherent)
        for (int i = tid; i < NHALO; i += TPB) {
            int lr, lc;
            if (i < 136)      { lr = i / 68;               lc = i % 68; }
            else if (i < 272) { const int j = i - 136; lr = 66 + j / 68; lc = j % 68; }
            else if (i < 400) { const int j = i - 272; lr = 2 + (j & 63); lc = j >> 6; }
            else              { const int j = i - 400; lr = 2 + (j & 63); lc = 66 + (j >> 6); }
            const int gy = min(max(ty0 - 2 + lr, 0), NYg - 1);
            const int gx = min(max(tx0 - 2 + lc, 0), NXg - 1);
            Sl[lr * SW + lc] = coh_load(&g_S[gy * NXg + gx]);
        }
    };

    int sortedYear = -1;
    // degree-day SMB via sort + prefix/suffix tables (R5/R7/R8-validated numerics)
    auto smb_refresh = [&](int yi) {
        if (yi != sortedYear) {
            sortedYear = yi;
            __syncthreads();
            if (tid < 365) { Ts[tid] = ldin(Td, yi * 365 + tid, f32);
                             Ps[tid] = ldin(Pd, yi * 365 + tid, f32); }
            else           { Ts[tid] = 3.0e38f; Ps[tid] = 0.0f; }
            __syncthreads();
            for (int kk = 2; kk <= 512; kk <<= 1)         // bitonic (T key, P payload)
                for (int j = kk >> 1; j > 0; j >>= 1) {
                    const int i = tid, ixj = i ^ j;
                    if (ixj > i) {
                        const bool up = ((i & kk) == 0);
                        const float a = Ts[i], c = Ts[ixj];
                        if ((a > c) == up) {
                            Ts[i] = c; Ts[ixj] = a;
                            const float p = Ps[i]; Ps[i] = Ps[ixj]; Ps[ixj] = p;
                        }
                    }
                    __syncthreads();
                }
            Js[tid] = (tid < 365) ? Ts[tid] : 0.0f;
            __syncthreads();
            for (int off = 1; off < 512; off <<= 1) {     // prefix(P) | suffix(T)
                const float p = Ps[tid] + ((tid >= off) ? Ps[tid - off] : 0.0f);
                const float q = Js[tid] + ((tid + off < 512) ? Js[tid + off] : 0.0f);
                __syncthreads();
                Ps[tid] = p; Js[tid] = q;
                __syncthreads();
            }
        }
        #pragma unroll
        for (int k = 0; k < 8; ++k) {
            const int r = r0 + 8 * k;
            const float zs = Sl[(r + 2) * SW + col + 2];  // current surface
            const float u = 0.006f * (zs - 1500.0f);      // GAMMA*(Zs-Z_REF)
            int lo = 0, hi = 365;                          // first idx with T > u
            while (lo < hi) { const int mid = (lo + hi) >> 1;
                              if (Ts[mid] <= u) lo = mid + 1; else hi = mid; }
            const float acc = (lo > 0) ? Ps[lo - 1] : 0.0f;
            const float pdd = (lo < 365)
                ? fmaxf(Js[lo] - u * (float)(365 - lo), 0.0f) : 0.0f;
            SMB[k] = Mb[k] ? (acc - mf * pdd) : -10.0f;    // mask==0 -> -10
        }
    };

    __syncthreads();
    smb_refresh(115);                              // year_idx(1979.0)=115, init surface
    gen_barrier();                                 // slots zeroed + frame(0) visible

    float t = 1979.0f, t_last = 0.0f;
    int prev_yi = 115;
    bool c26 = false, c57 = false, c80 = false;

    for (int step = 0; step < NSTEP; ++step) {
        // ---- 1. neighbor ring wait (8-thread pairwise flags) + halo load ----
        if (step > 0) {
            if (tid < 8) {
                const int d = (tid < 4) ? tid : tid + 1;   // skip (0,0)
                const int nby = by + d / 3 - 1, nbx = bx + d % 3 - 1;
                if (nby >= 0 && nby < NBY && nbx >= 0 && nbx < NBX) {
                    const int nb = nby * NBX + nbx;
                    while (__hip_atomic_load(&g_flag[step][nb], __ATOMIC_ACQUIRE,
                                             __HIP_MEMORY_SCOPE_AGENT) == 0u)
                        __builtin_amdgcn_s_sleep(1);
                }
            }
            __syncthreads();
        }
        load_halo();
        __syncthreads();

        // ---- 2. D on 1-halo + block max ----
        float dmax = 0.0f;
        for (int i = tid; i < DW * DW; i += TPB) {
            const int lr = i / DW, lc = i % DW;
            const int gy = ty0 - 1 + lr, gx = tx0 - 1 + lc;   // may be off-grid
            const int si = (lr + 1) * SW + (lc + 1);
            const float sc = Sl[si];
            const int cgx = min(max(gx, 0), NXg - 1), cgy = min(max(gy, 0), NYg - 1);
            // jnp.gradient: central interior, one-sided first-order edges
            const float gxv = (cgx == 0)       ? (Sl[si + 1] - sc) * I1HX
                            : (cgx == NXg - 1) ? (sc - Sl[si - 1]) * I1HX
                                               : (Sl[si + 1] - Sl[si - 1]) * I2HX;
            const float gyv = (cgy == 0)       ? (Sl[si + SW] - sc) * I1HX
                            : (cgy == NYg - 1) ? (sc - Sl[si - SW]) * I1HX
                                               : (Sl[si + SW] - Sl[si - SW]) * I2HX;
            const float h = sc - Zl[i];
            const float h2 = h * h;
            const float D = (PHYS_C * (h2 * h2 * h)) * (gxv * gxv + gyv * gyv);
            Dl[i] = D;
            if (gy >= 0 && gy < NYg && gx >= 0 && gx < NXg) dmax = fmaxf(dmax, D);
        }
        for (int off = 32; off; off >>= 1) dmax = fmaxf(dmax, __shfl_down(dmax, off));
        if ((tid & 63) == 0) wred[tid >> 6] = dmax;
        __syncthreads();

        // ---- 3a. post block max: single store, complement-encoded (0=not ready) ----
        if (tid == 0) {
            float m = wred[0];
            #pragma unroll
            for (int i = 1; i < 8; ++i) m = fmaxf(m, wred[i]);
            __hip_atomic_store(&g_bmax[step][b], ~__float_as_uint(m),
                               __ATOMIC_RELAXED, __HIP_MEMORY_SCOPE_AGENT);
        }

        // ---- 3b. dt-independent divergence — hides the store/poll round-trip ----
        float divv[8];
        #pragma unroll
        for (int k = 0; k < 8; ++k) {
            const int r = r0 + 8 * k;
            const int gy = ty0 + r, gx = tx0 + col;
            const int si = (r + 2) * SW + col + 2;
            const int di = (r + 1) * DW + col + 1;
            const float sc = Sl[si], dc = Dl[di];
            float qxR = 0.0f, qxL = 0.0f, qyU = 0.0f, qyD = 0.0f;  // zero-flux bnd
            if (gx < NXg - 1) qxR = 0.5f * (Dl[di + 1] + dc)  * ((Sl[si + 1] - sc)  * I1HX);
            if (gx > 0)       qxL = 0.5f * (dc + Dl[di - 1])  * ((sc - Sl[si - 1])  * I1HX);
            if (gy < NYg - 1) qyU = 0.5f * (Dl[di + DW] + dc) * ((Sl[si + SW] - sc) * I1HX);
            if (gy > 0)       qyD = 0.5f * (dc + Dl[di - DW]) * ((sc - Sl[si - SW]) * I1HX);
            divv[k] = (qxR - qxL) * I1HX + (qyU - qyD) * I1HX;
        }
        __syncthreads();                           // divv reads done; Sl may be rewritten

        // ---- 3c. direct-read global max: wave 0 polls the 64 slots ----
        if (tid < 64) {
            unsigned v;
            while ((v = __hip_atomic_load(&g_bmax[step][tid], __ATOMIC_RELAXED,
                                          __HIP_MEMORY_SCOPE_AGENT)) == 0u)
                __builtin_amdgcn_s_sleep(1);
            float dv = __uint_as_float(~v);
            for (int off = 32; off; off >>= 1) dv = fmaxf(dv, __shfl_xor(dv, off));
            if (tid == 0) wred[0] = dv;
        }
        __syncthreads();
        const float maxD = wred[0];

        // ---- 4. dt, H update, Sl rewrite, ring publish (from registers) ----
        const float dt = fminf(0.1f, 2000.0f / (maxD + 1e-6f));   // CFL*dx^2 = 2000
        const float tn = t + dt;
        const bool hit26 = !c26 && (tn >= 1926.0f);
        const bool hit57 = !c57 && (tn >= 1957.0f);
        const bool hit80 = !c80 && (tn >= 1980.0f);
        #pragma unroll
        for (int k = 0; k < 8; ++k) {
            const int r = r0 + 8 * k;
            const int si = (r + 2) * SW + col + 2;
            const int di = (r + 1) * DW + col + 1;
            const float hn = fmaxf(H[k] + dt * (SMB[k] + divv[k]), 0.0f);
            H[k] = hn;
            const float s_new = Zl[di] + hn;
            Sl[si] = s_new;
            if (Ring[k]) coh_store(&g_S[(ty0 + r) * NXg + tx0 + col], s_new);
        }
        __syncthreads();                           // drains vmcnt: ring stores retired

        // ---- 5. flag ASAP, then snapshots + SMB refresh off the critical path ----
        if (tid == 0)
            __hip_atomic_store(&g_flag[step + 1][b], 1u, __ATOMIC_RELEASE,
                               __HIP_MEMORY_SCOPE_AGENT);
        if (hit26 | hit57 | hit80) {
            #pragma unroll
            for (int k = 0; k < 8; ++k) {
                const int g = (ty0 + r0 + 8 * k) * NXg + tx0 + col;
                if (hit26) stout(Out, g, H[k], f32);
                if (hit57) stout(Out, NCELL + g, H[k], f32);
                if (hit80) stout(Out, 2 * NCELL + g, H[k], f32);
            }
        }
        c26 |= hit26; c57 |= hit57; c80 |= hit80;

        int yi = (int)floorf(tn - 1864.0f);
        yi = min(max(yi, 0), 127);
        const bool need = (yi != prev_yi) || (tn - t_last >= 10.0f);
        if (need) {
            t_last = tn; prev_yi = yi;
            if (tn < 1981.0f) smb_refresh(yi);     // same year -> no re-sort, just search
        }
        t = tn;
        if (t >= 1981.0f) break;                   // uniform across grid (same dt chain)
    }

    // ---- finals: H always; zeros for untriggered snapshots ----
    #pragma unroll
    for (int k = 0; k < 8; ++k) {
        const int g = (ty0 + r0 + 8 * k) * NXg + tx0 + col;
        stout(Out, 3 * NCELL + g, H[k], f32);
        if (!c26) stout(Out, g, 0.0f, f32);
        if (!c57) stout(Out, NCELL + g, 0.0f, f32);
        if (!c80) stout(Out, 2 * NCELL + g, 0.0f, f32);
    }
}

extern "C" void kernel_launch(void* const* d_in, const int* in_sizes, int n_in,
                              void* d_out, int out_size, void* d_ws, size_t ws_size,
                              hipStream_t stream) {
    (void)in_sizes; (void)n_in; (void)out_size; (void)d_ws; (void)ws_size;
    const void* Zt = d_in[0];   // Z_topo
    const void* Hi = d_in[1];   // H_init
    const void* Mk = d_in[2];   // ice_mask
    // d_in[3] precip_tensor, d_in[4] T_m_lowest, d_in[5] T_s: unused by reference
    const void* Pd = d_in[6];   // P_daily
    const void* Td = d_in[7];   // T_daily
    const void* Mf = d_in[8];   // melt_factor
    hipLaunchKernelGGL(GlacierDynamicsCheckpointed_41412074668209_kernel,
                       dim3(NBLK), dim3(TPB), 0, stream,
                       Zt, Hi, Mk, Pd, Td, Mf, d_out);
}